// Round 2
// baseline (275.777 us; speedup 1.0000x reference)
//
#include <hip/hip_runtime.h>
#include <hip/hip_fp16.h>

// GCN encoder: 3x (GCNConv + ReLU), dims 256->128->64->32
// N=50000 nodes, E=800000 edges. edge_index delivered as int32 (harness).
// R2: CSR gather.  R3/R11: multi-block scan, fused.  R5: fp16 H buffers.
// R6: MFMA gemms.  R7: atomic-free fill via rank.  R10: persistent-B gemm.
// R12: gemm1 fused INTO the histogram kernel.
// R13: gemm2/gemm3 fused into agg1/agg2 epilogues (LDS-staged MFMA).
// R14: device-atomic histogram REPLACED by LDS histograms.
//      Measured: device-scope 64b returning atomics cap at ~12 G/s
//      (replication-invariant) -> 66us wall. Now: 8 node-ranges x 32 edge
//      slices; block (r,s) builds a 6250-entry LDS histogram (ds_add_rtn_u64,
//      per-CU, no fabric), records per-(r,s) local rank, flushes partials.
//      scan_reduce folds 32 partials/node + emits base16 slice-prefix table;
//      fill slot = row_ptr[c] + base16[s][c] + rank[e]. Degree sums are
//      bit-identical (integer fixed-point). No global memset needed.

#define D0 256
#define D1 128
#define D2 64
#define D3 32

#define NRANGE 8
#define NSLICE 32
#define RN_MAX 6256                     // LDS histogram entries (>= ceil(N/NRANGE))

#define FIX_SCALE 16777216.0f           // 2^24 fixed-point for degree
#define FIX_INV   (1.0f / 16777216.0f)

typedef _Float16 half8 __attribute__((ext_vector_type(8)));
typedef float floatx4 __attribute__((ext_vector_type(4)));

// ------------------------------------------------------ gemm device core ---
// H[N,BN] (fp16) = X[N,K] @ W[K,BN] (both possibly fp32, cvt in-register).
// A[m=lane&15][k=quad*8+j]; B[k][n]; D row=quad*4+reg.
template <typename SRC>
__device__ __forceinline__ half8 loadA(const SRC* __restrict__ p) {
    if constexpr (sizeof(SRC) == 4) {
        float4 f0 = *(const float4*)p;
        float4 f1 = *(const float4*)(p + 4);
        half8 v;
        v[0] = (_Float16)f0.x; v[1] = (_Float16)f0.y;
        v[2] = (_Float16)f0.z; v[3] = (_Float16)f0.w;
        v[4] = (_Float16)f1.x; v[5] = (_Float16)f1.y;
        v[6] = (_Float16)f1.z; v[7] = (_Float16)f1.w;
        return v;
    } else {
        return *(const half8*)p;
    }
}

template <int K, int BN, typename SRC>
__device__ __forceinline__ void gemm_work(const SRC* __restrict__ X,
                                          const float* __restrict__ W,
                                          _Float16* __restrict__ H, int N,
                                          int w, int totalWaves) {
    constexpr int NC = K / 32;        // k-chunks
    constexpr int CG = BN / 32;       // col groups (waves per slab)
    const int lane = threadIdx.x & 63;
    const int quad = lane >> 4;
    const int m = lane & 15;
    const int cg = w & (CG - 1);
    const int nslab = N >> 4;         // N multiple of 16
    const int stride = totalWaves / CG;
    int slab = w / CG;
    if (slab >= nslab) return;
    const int n0 = cg * 32;

    // ---- persistent B-frags: W fp32, strided, loaded once per wave ----
    half8 b0[NC], b1[NC];
#pragma unroll
    for (int c = 0; c < NC; ++c) {
#pragma unroll
        for (int j = 0; j < 8; ++j) {
            int k = c * 32 + quad * 8 + j;
            b0[c][j] = (_Float16)W[(size_t)k * BN + n0 + m];
            b1[c][j] = (_Float16)W[(size_t)k * BN + n0 + 16 + m];
        }
    }

    half8 a[NC];
#pragma unroll
    for (int c = 0; c < NC; ++c)
        a[c] = loadA(&X[(size_t)(slab * 16 + m) * K + c * 32 + quad * 8]);

    while (true) {
        const int next = slab + stride;
        half8 an[NC];
        if (next < nslab) {
#pragma unroll
            for (int c = 0; c < NC; ++c)
                an[c] = loadA(&X[(size_t)(next * 16 + m) * K + c * 32 + quad * 8]);
        }

        floatx4 acc0 = (floatx4){0.f, 0.f, 0.f, 0.f};
        floatx4 acc1 = (floatx4){0.f, 0.f, 0.f, 0.f};
#pragma unroll
        for (int c = 0; c < NC; ++c) {
            acc0 = __builtin_amdgcn_mfma_f32_16x16x32_f16(a[c], b0[c], acc0, 0, 0, 0);
            acc1 = __builtin_amdgcn_mfma_f32_16x16x32_f16(a[c], b1[c], acc1, 0, 0, 0);
        }

        const int r0 = slab * 16 + quad * 4;
#pragma unroll
        for (int r = 0; r < 4; ++r) {
            H[(size_t)(r0 + r) * BN + n0 + m]      = (_Float16)acc0[r];
            H[(size_t)(r0 + r) * BN + n0 + 16 + m] = (_Float16)acc1[r];
        }

        if (next >= nslab) break;
        slab = next;
#pragma unroll
        for (int c = 0; c < NC; ++c) a[c] = an[c];
    }
}

// --------------------- fused LDS histogram + gemm1 (independent work) ------
// Blocks [0, hB): histogram. Block (range r = b&7, slice s = b>>3) scans its
// edge slice; cols inside its node range accumulate (count|wfix) into LDS
// via ds_add_rtn_u64 (per-CU, no device-scope fabric traffic). old>>32 is
// the edge's local rank within (r,s). Partials flushed to part[s][node].
// Blocks [hB, hB+gB): gemm1 (x fp32 @ W1 fp32 -> h1 fp16).
__global__ __launch_bounds__(256) void hist_gemm1_kernel(
        const float* __restrict__ x, const float* __restrict__ W1,
        _Float16* __restrict__ h1, int N,
        const int* __restrict__ ei, const float* __restrict__ ew,
        unsigned long long* __restrict__ part, int* __restrict__ rank, int E,
        int hB, int gB) {
    __shared__ unsigned long long hlds[RN_MAX];
    const int b = blockIdx.x;
    if (b >= hB) {
        gemm_work<D0, D1, float>(x, W1, h1, N,
                                 (b - hB) * 4 + (threadIdx.x >> 6), gB * 4);
        return;
    }
    const int t = threadIdx.x;
    const int r = b & (NRANGE - 1);
    const int s = b >> 3;                       // NRANGE == 8
    const int RNv = (N + NRANGE - 1) / NRANGE;  // 6250
    const int r0 = r * RNv;
    const int rcnt = min(RNv, N - r0);

    for (int i = t; i < rcnt; i += 256) hlds[i] = 0ULL;
    __syncthreads();

    const int SE = (E + NSLICE - 1) / NSLICE;   // 25000
    const int e0 = s * SE;
    const int e1 = min(e0 + SE, E);
    for (int e = e0 + t; e < e1; e += 256) {
        int c = ei[E + e];
        unsigned rc = (unsigned)(c - r0);
        if (rc < (unsigned)rcnt) {
            unsigned wfix = (unsigned)(ew[e] * FIX_SCALE + 0.5f);
            unsigned long long old =
                atomicAdd(&hlds[rc], (1ULL << 32) | (unsigned long long)wfix);
            rank[e] = (int)(old >> 32);
        }
    }
    __syncthreads();

    unsigned long long* dst = part + (size_t)s * N + r0;
    for (int i = t; i < rcnt; i += 256) dst[i] = hlds[i];
}

// --------------------------------------------- 2-phase exclusive scan ------
// Folds the NSLICE partials per node: deg = sum of fixed-point parts
// (+1 self loop), cnt = total count, base16[s][node] = exclusive prefix of
// per-slice counts (for CSR slot reconstruction).
__global__ __launch_bounds__(256) void scan_reduce(const unsigned long long* __restrict__ part,
                                                   float* __restrict__ dinv,
                                                   int* __restrict__ cnt,
                                                   unsigned short* __restrict__ base16,
                                                   int* __restrict__ blockSum, int N) {
    __shared__ int sred[256];
    const int t = threadIdx.x;
    const int i = blockIdx.x * 256 + t;
    int v = 0;
    if (i < N) {
        unsigned run = 0;
        unsigned wsum = 0;
#pragma unroll
        for (int s = 0; s < NSLICE; ++s) {
            unsigned long long p = part[(size_t)s * N + i];
            base16[(size_t)s * N + i] = (unsigned short)run;
            run += (unsigned)(p >> 32);
            wsum += (unsigned)p;
        }
        float d = (float)wsum * FIX_INV + 1.0f;   // +1 self-loop
        dinv[i] = rsqrtf(d);
        v = (int)run;
        cnt[i] = v;
    }
    sred[t] = v;
    __syncthreads();
#pragma unroll
    for (int off = 128; off > 0; off >>= 1) {
        if (t < off) sred[t] += sred[t + off];
        __syncthreads();
    }
    if (t == 0) blockSum[blockIdx.x] = sred[0];
}

__global__ __launch_bounds__(256) void scan_apply(const int* __restrict__ cnt,
                                                  const int* __restrict__ blockSum,
                                                  int* __restrict__ row_ptr, int N, int B) {
    __shared__ int bs[256];
    __shared__ int s[256];
    const int t = threadIdx.x;
    bs[t] = (t < B) ? blockSum[t] : 0;
    __syncthreads();
#pragma unroll
    for (int off = 1; off < 256; off <<= 1) {
        int u = (t >= off) ? bs[t - off] : 0;
        __syncthreads();
        bs[t] += u;
        __syncthreads();
    }
    const int myOff = (blockIdx.x > 0) ? bs[blockIdx.x - 1] : 0;
    const int i = blockIdx.x * 256 + t;
    const int v = (i < N) ? cnt[i] : 0;
    s[t] = v;
    __syncthreads();
#pragma unroll
    for (int off = 1; off < 256; off <<= 1) {
        int u = (t >= off) ? s[t - off] : 0;
        __syncthreads();
        s[t] += u;
        __syncthreads();
    }
    if (i < N) row_ptr[i] = s[t] - v + myOff;
    if (blockIdx.x == 0 && t == 0) row_ptr[N] = bs[B - 1];
}

// ------------------------------------------------- bucket fill (CSR) -------
__global__ void fill_kernel(const int* __restrict__ ei, const float* __restrict__ ew,
                            const float* __restrict__ dinv,
                            const int* __restrict__ row_ptr, const int* __restrict__ rank,
                            const unsigned short* __restrict__ base16,
                            int2* __restrict__ pairs, int E, int N, int SE) {
    int e = blockIdx.x * blockDim.x + threadIdx.x;
    if (e < E) {
        int r = ei[e];
        int c = ei[E + e];
        float w = dinv[r] * ew[e] * dinv[c];
        int s = e / SE;
        int slot = row_ptr[c] + (int)base16[(size_t)s * N + c] + rank[e];
        pairs[slot] = make_int2(r, __float_as_int(w));
    }
}

// ------------------------- fused aggregate + epilogue + NEXT-LAYER gemm ----
// Gather/scale/bias/relu; post-ReLU rows staged in LDS; block-local MFMA gemm
// produces the next layer's linear output (fp16 A/B, fp32 acc).
template <int DIN, int DOUT>
__global__ __launch_bounds__(256) void agg_gemm_kernel(
        const _Float16* __restrict__ H, const int* __restrict__ row_ptr,
        const int2* __restrict__ pairs, const float* __restrict__ dinv,
        const float* __restrict__ bias, const float* __restrict__ W,
        _Float16* __restrict__ Hout, int N) {
    constexpr int TPN = DIN / 8;      // threads per node
    constexpr int NPB = 256 / TPN;    // nodes per block
    constexpr int NC  = DIN / 32;     // gemm k-chunks
    constexpr int S   = NPB / 16;     // 16-row slabs per block
    constexpr int T   = DOUT / 16;    // 16-col tiles
    static_assert(S * T == 4, "one tile per wave");
    __shared__ _Float16 sA[NPB][DIN + 8];

    const int tid = threadIdx.x;
    const int g = tid / TPN;
    const int sl = tid % TPN;
    const int node0 = blockIdx.x * NPB;
    const int node = node0 + g;
    const bool valid = node < N;

    // ---- hoisted B-frags (fp32 W, loop-invariant; loads hide under gather) --
    const int w = tid >> 6;
    const int lane = tid & 63;
    const int q = lane >> 4;
    const int m = lane & 15;
    const int s = w & (S - 1);
    const int t = w / S;
    half8 bf[NC];
#pragma unroll
    for (int c = 0; c < NC; ++c) {
#pragma unroll
        for (int j = 0; j < 8; ++j)
            bf[c][j] = (_Float16)W[(size_t)(c * 32 + q * 8 + j) * DOUT + t * 16 + m];
    }

    float acc[8];
#pragma unroll
    for (int j = 0; j < 8; ++j) acc[j] = 0.0f;

    int beg = 0, end = 0;
    if (valid) { beg = row_ptr[node]; end = row_ptr[node + 1]; }

    if (end > beg) {
        const int last = end - 1;
        int2 p0 = pairs[beg];
        int2 p1 = pairs[min(beg + 1, last)];
        int2 p2 = pairs[min(beg + 2, last)];
        half8 u0 = *(const half8*)&H[(size_t)p0.x * DIN + sl * 8];
        half8 u1 = *(const half8*)&H[(size_t)p1.x * DIN + sl * 8];
        for (int k = beg; k < end; ++k) {
            int2 p3 = pairs[min(k + 3, last)];
            half8 u2 = *(const half8*)&H[(size_t)p2.x * DIN + sl * 8];
            float wv = __int_as_float(p0.y);
#pragma unroll
            for (int j = 0; j < 8; ++j) acc[j] = fmaf(wv, (float)u0[j], acc[j]);
            p0 = p1; p1 = p2; p2 = p3;
            u0 = u1; u1 = u2;
        }
    }

    if (valid) {
        // self-loop + bias + relu -> LDS (this IS the out row, fp16)
        float di = dinv[node];
        float d2 = di * di;
        half8 u = *(const half8*)&H[(size_t)node * DIN + sl * 8];
#pragma unroll
        for (int j = 0; j < 8; ++j) acc[j] = fmaf(d2, (float)u[j], acc[j]);
        float bb[8];
        *(float4*)&bb[0] = *(const float4*)&bias[sl * 8];
        *(float4*)&bb[4] = *(const float4*)&bias[sl * 8 + 4];
        half8 o;
#pragma unroll
        for (int j = 0; j < 8; ++j) o[j] = (_Float16)fmaxf(acc[j] + bb[j], 0.f);
        *(half8*)&sA[g][sl * 8] = o;
    }
    __syncthreads();

    // ---- next-layer gemm on the block's rows ----
    half8 a[NC];
#pragma unroll
    for (int c = 0; c < NC; ++c)
        a[c] = *(const half8*)&sA[s * 16 + m][c * 32 + q * 8];
    floatx4 o4 = (floatx4){0.f, 0.f, 0.f, 0.f};
#pragma unroll
    for (int c = 0; c < NC; ++c)
        o4 = __builtin_amdgcn_mfma_f32_16x16x32_f16(a[c], bf[c], o4, 0, 0, 0);
#pragma unroll
    for (int r = 0; r < 4; ++r) {
        const int nr = node0 + s * 16 + q * 4 + r;
        if (nr < N) Hout[(size_t)nr * DOUT + t * 16 + m] = (_Float16)o4[r];
    }
}

// -------------------------------------- final aggregate + epilogue (fp32) --
template <int D, typename OUT>
__global__ __launch_bounds__(256) void agg_kernel(const _Float16* __restrict__ H,
                                                  const int* __restrict__ row_ptr,
                                                  const int2* __restrict__ pairs,
                                                  const float* __restrict__ dinv,
                                                  const float* __restrict__ bias,
                                                  OUT* __restrict__ out, int N) {
    constexpr int TPN = D / 8;
    constexpr int NPB = 256 / TPN;
    const int tid = threadIdx.x;
    const int g = tid / TPN;
    const int lane = tid % TPN;
    const int node = blockIdx.x * NPB + g;
    if (node >= N) return;

    const int beg = row_ptr[node];
    const int end = row_ptr[node + 1];
    float acc[8];
#pragma unroll
    for (int j = 0; j < 8; ++j) acc[j] = 0.0f;

    if (end > beg) {
        const int last = end - 1;
        int2 p0 = pairs[beg];
        int2 p1 = pairs[min(beg + 1, last)];
        int2 p2 = pairs[min(beg + 2, last)];
        half8 u0 = *(const half8*)&H[(size_t)p0.x * D + lane * 8];
        half8 u1 = *(const half8*)&H[(size_t)p1.x * D + lane * 8];
        for (int k = beg; k < end; ++k) {
            int2 p3 = pairs[min(k + 3, last)];
            half8 u2 = *(const half8*)&H[(size_t)p2.x * D + lane * 8];
            float w = __int_as_float(p0.y);
#pragma unroll
            for (int j = 0; j < 8; ++j) acc[j] = fmaf(w, (float)u0[j], acc[j]);
            p0 = p1; p1 = p2; p2 = p3;
            u0 = u1; u1 = u2;
        }
    }
    float di = dinv[node];
    float d2 = di * di;
    {
        half8 u = *(const half8*)&H[(size_t)node * D + lane * 8];
#pragma unroll
        for (int j = 0; j < 8; ++j) acc[j] = fmaf(d2, (float)u[j], acc[j]);
    }
    float b[8];
    *(float4*)&b[0] = *(const float4*)&bias[lane * 8];
    *(float4*)&b[4] = *(const float4*)&bias[lane * 8 + 4];
#pragma unroll
    for (int j = 0; j < 8; ++j) acc[j] = fmaxf(acc[j] + b[j], 0.f);

    if constexpr (sizeof(OUT) == 2) {
        half8 o;
#pragma unroll
        for (int j = 0; j < 8; ++j) o[j] = (_Float16)acc[j];
        *(half8*)&out[(size_t)node * D + lane * 8] = o;
    } else {
        float* dst = (float*)&out[(size_t)node * D + lane * 8];
        *(float4*)&dst[0] = make_float4(acc[0], acc[1], acc[2], acc[3]);
        *(float4*)&dst[4] = make_float4(acc[4], acc[5], acc[6], acc[7]);
    }
}

// ---------------------------------------------------------------- launch ----
extern "C" void kernel_launch(void* const* d_in, const int* in_sizes, int n_in,
                              void* d_out, int out_size, void* d_ws, size_t ws_size,
                              hipStream_t stream) {
    const float* x   = (const float*)d_in[0];
    const int* ei    = (const int*)d_in[1];
    const float* ew  = (const float*)d_in[2];
    const float* W1  = (const float*)d_in[3];
    const float* b1  = (const float*)d_in[4];
    const float* W2  = (const float*)d_in[5];
    const float* b2  = (const float*)d_in[6];
    const float* W3  = (const float*)d_in[7];
    const float* b3  = (const float*)d_in[8];
    float* out = (float*)d_out;

    const int N = in_sizes[0] / D0;   // 50000
    const int E = in_sizes[2];        // 800000
    (void)n_in; (void)out_size; (void)ws_size;

    // ---- workspace carving ----
    char* ws = (char*)d_ws;
    size_t off = 0;
    auto carve = [&](size_t bytes) -> void* {
        void* p = (void*)(ws + off);
        off += (bytes + 255) & ~(size_t)255;
        return p;
    };
    float* dinv    = (float*)carve((size_t)N * 4);
    int*   cnt     = (int*)carve((size_t)N * 4);
    int*   row_ptr = (int*)carve((size_t)(N + 1) * 4);
    int*   rank    = (int*)carve((size_t)E * 4);
    int*   bsum    = (int*)carve(256 * 4);
    unsigned short* base16 = (unsigned short*)carve((size_t)N * NSLICE * 2);
    int2*  pairs   = (int2*)carve((size_t)E * 8);
    _Float16* bufH = (_Float16*)carve((size_t)N * D1 * 2);
    // part (N*NSLICE*8 = 12.8MB) aliases bufO (N*D1*2 = 12.8MB): part is dead
    // after scan_reduce; h2 is written later (agg_gemm1).
    size_t unionBytes = (size_t)N * NSLICE * 8;
    if ((size_t)N * D1 * 2 > unionBytes) unionBytes = (size_t)N * D1 * 2;
    char* uni = (char*)carve(unionBytes);
    unsigned long long* part = (unsigned long long*)uni;
    _Float16* bufO = (_Float16*)uni;

    _Float16* h1 = bufH;              // N x 128 fp16 (gemm1 out)
    _Float16* h2 = bufO;              // N x 64  fp16 (agg1+gemm2 out)
    _Float16* h3 = bufH;              // N x 32  fp16 (agg2+gemm3 out; h1 dead)

    const int eb = (E + 255) / 256;       // 3125
    const int scanB = (N + 255) / 256;    // 196 (must be <= 256)
    const int hB = NRANGE * NSLICE;       // 256 histogram blocks (50KB LDS each)
    const int gB = 512;                   // gemm blocks; hB+gB = 768 = 3/CU (LDS cap)
    const int SE = (E + NSLICE - 1) / NSLICE;

    // ---- fused: LDS histogram + gemm1 (independent, one dispatch) ----
    hist_gemm1_kernel<<<hB + gB, 256, 0, stream>>>(
        x, W1, h1, N, ei, ew, part, rank, E, hB, gB);

    // ---- CSR build ----
    scan_reduce<<<scanB, 256, 0, stream>>>(part, dinv, cnt, base16, bsum, N);
    scan_apply<<<scanB, 256, 0, stream>>>(cnt, bsum, row_ptr, N, scanB);
    fill_kernel<<<eb, 256, 0, stream>>>(ei, ew, dinv, row_ptr, rank, base16, pairs, E, N, SE);

    // ---- layer 1 aggregate (+ fused gemm2: 128 -> 64) ----
    agg_gemm_kernel<D1, D2><<<(N + 15) / 16, 256, 0, stream>>>(
        h1, row_ptr, pairs, dinv, b1, W2, h2, N);

    // ---- layer 2 aggregate (+ fused gemm3: 64 -> 32) ----
    agg_gemm_kernel<D2, D3><<<(N + 31) / 32, 256, 0, stream>>>(
        h2, row_ptr, pairs, dinv, b2, W3, h3, N);

    // ---- layer 3 aggregate + epilogue (fp32 out) ----
    agg_kernel<D3, float><<<(N + 63) / 64, 256, 0, stream>>>(
        h3, row_ptr, pairs, dinv, b3, out, N);
}

// Round 3
// 267.164 us; speedup vs baseline: 1.0322x; 1.0322x over previous
//
#include <hip/hip_runtime.h>
#include <hip/hip_fp16.h>

// GCN encoder: 3x (GCNConv + ReLU), dims 256->128->64->32
// N=50000 nodes, E=800000 edges. edge_index delivered as int32 (harness).
// R2: CSR gather.  R3/R11: multi-block scan, fused.  R5: fp16 H buffers.
// R6: MFMA gemms.  R7: atomic-free fill via rank.  R10: persistent-B gemm.
// R12: gemm1 fused INTO the histogram kernel.
// R13: gemm2/gemm3 fused into agg1/agg2 epilogues (LDS-staged MFMA).
// R14: LDS histograms (range x slice) instead of device atomics (12 G/s cap).
// R15: R14 was latency-bound (98 serial dependent iters/thread -> 90us).
//      Fix: 4-wide vectorized edge loads with next-group prefetch (24 iters,
//      load latency hidden), NRANGE 8->16 (25KB LDS -> ~6 blocks/CU, 512 hist
//      blocks), gB back to 768. Partials table unchanged (indexed slice,node).

#define D0 256
#define D1 128
#define D2 64
#define D3 32

#define NRANGE 16
#define NSLICE 32
#define RN_MAX 3200                     // LDS histogram entries (>= ceil(N/NRANGE))

#define FIX_SCALE 16777216.0f           // 2^24 fixed-point for degree
#define FIX_INV   (1.0f / 16777216.0f)

typedef _Float16 half8 __attribute__((ext_vector_type(8)));
typedef float floatx4 __attribute__((ext_vector_type(4)));

// ------------------------------------------------------ gemm device core ---
// H[N,BN] (fp16) = X[N,K] @ W[K,BN] (both possibly fp32, cvt in-register).
// A[m=lane&15][k=quad*8+j]; B[k][n]; D row=quad*4+reg.
template <typename SRC>
__device__ __forceinline__ half8 loadA(const SRC* __restrict__ p) {
    if constexpr (sizeof(SRC) == 4) {
        float4 f0 = *(const float4*)p;
        float4 f1 = *(const float4*)(p + 4);
        half8 v;
        v[0] = (_Float16)f0.x; v[1] = (_Float16)f0.y;
        v[2] = (_Float16)f0.z; v[3] = (_Float16)f0.w;
        v[4] = (_Float16)f1.x; v[5] = (_Float16)f1.y;
        v[6] = (_Float16)f1.z; v[7] = (_Float16)f1.w;
        return v;
    } else {
        return *(const half8*)p;
    }
}

template <int K, int BN, typename SRC>
__device__ __forceinline__ void gemm_work(const SRC* __restrict__ X,
                                          const float* __restrict__ W,
                                          _Float16* __restrict__ H, int N,
                                          int w, int totalWaves) {
    constexpr int NC = K / 32;        // k-chunks
    constexpr int CG = BN / 32;       // col groups (waves per slab)
    const int lane = threadIdx.x & 63;
    const int quad = lane >> 4;
    const int m = lane & 15;
    const int cg = w & (CG - 1);
    const int nslab = N >> 4;         // N multiple of 16
    const int stride = totalWaves / CG;
    int slab = w / CG;
    if (slab >= nslab) return;
    const int n0 = cg * 32;

    // ---- persistent B-frags: W fp32, strided, loaded once per wave ----
    half8 b0[NC], b1[NC];
#pragma unroll
    for (int c = 0; c < NC; ++c) {
#pragma unroll
        for (int j = 0; j < 8; ++j) {
            int k = c * 32 + quad * 8 + j;
            b0[c][j] = (_Float16)W[(size_t)k * BN + n0 + m];
            b1[c][j] = (_Float16)W[(size_t)k * BN + n0 + 16 + m];
        }
    }

    half8 a[NC];
#pragma unroll
    for (int c = 0; c < NC; ++c)
        a[c] = loadA(&X[(size_t)(slab * 16 + m) * K + c * 32 + quad * 8]);

    while (true) {
        const int next = slab + stride;
        half8 an[NC];
        if (next < nslab) {
#pragma unroll
            for (int c = 0; c < NC; ++c)
                an[c] = loadA(&X[(size_t)(next * 16 + m) * K + c * 32 + quad * 8]);
        }

        floatx4 acc0 = (floatx4){0.f, 0.f, 0.f, 0.f};
        floatx4 acc1 = (floatx4){0.f, 0.f, 0.f, 0.f};
#pragma unroll
        for (int c = 0; c < NC; ++c) {
            acc0 = __builtin_amdgcn_mfma_f32_16x16x32_f16(a[c], b0[c], acc0, 0, 0, 0);
            acc1 = __builtin_amdgcn_mfma_f32_16x16x32_f16(a[c], b1[c], acc1, 0, 0, 0);
        }

        const int r0 = slab * 16 + quad * 4;
#pragma unroll
        for (int r = 0; r < 4; ++r) {
            H[(size_t)(r0 + r) * BN + n0 + m]      = (_Float16)acc0[r];
            H[(size_t)(r0 + r) * BN + n0 + 16 + m] = (_Float16)acc1[r];
        }

        if (next >= nslab) break;
        slab = next;
#pragma unroll
        for (int c = 0; c < NC; ++c) a[c] = an[c];
    }
}

// ---------------------------------------------- edge 4-group loader --------
// Loads 4 cols + 4 weights; cols default to -1 (never matches) past e1.
__device__ __forceinline__ void load_grp(const int* __restrict__ ei,
                                         const float* __restrict__ ew,
                                         int E, int e, int e1, bool vec,
                                         int4& c, float4& w) {
    if (vec && e + 3 < e1) {
        c = *(const int4*)&ei[E + e];
        w = *(const float4*)&ew[e];
    } else {
        int* cp = (int*)&c;
        float* wp = (float*)&w;
#pragma unroll
        for (int i = 0; i < 4; ++i) {
            if (e + i < e1) { cp[i] = ei[E + e + i]; wp[i] = ew[e + i]; }
            else            { cp[i] = -1;            wp[i] = 0.f; }
        }
    }
}

// --------------------- fused LDS histogram + gemm1 (independent work) ------
// Blocks [0, hB): histogram. Block (range r = b&15, slice s = b>>4) scans its
// edge slice with 4-wide prefetched loads; cols inside its node range
// accumulate (count|wfix) into LDS via ds_add_rtn_u64. old>>32 is the edge's
// local rank within (r,s). Partials flushed to part[s][node].
// Blocks [hB, hB+gB): gemm1 (x fp32 @ W1 fp32 -> h1 fp16).
__global__ __launch_bounds__(256) void hist_gemm1_kernel(
        const float* __restrict__ x, const float* __restrict__ W1,
        _Float16* __restrict__ h1, int N,
        const int* __restrict__ ei, const float* __restrict__ ew,
        unsigned long long* __restrict__ part, int* __restrict__ rank, int E,
        int hB, int gB, int SE) {
    __shared__ unsigned long long hlds[RN_MAX];
    const int b = blockIdx.x;
    if (b >= hB) {
        gemm_work<D0, D1, float>(x, W1, h1, N,
                                 (b - hB) * 4 + (threadIdx.x >> 6), gB * 4);
        return;
    }
    const int t = threadIdx.x;
    const int r = b & (NRANGE - 1);
    const int s = b >> 4;                       // NRANGE == 16
    const int RNv = (N + NRANGE - 1) / NRANGE;  // 3125
    const int r0 = r * RNv;
    const int rcnt = min(RNv, N - r0);

    for (int i = t; i < rcnt; i += 256) hlds[i] = 0ULL;
    __syncthreads();

    const int e0 = s * SE;
    const int e1 = min(e0 + SE, E);
    const bool vec = ((E & 3) == 0);            // int4/float4 alignment
    const int estep = 256 * 4;

    int e = e0 + t * 4;
    int4 c_cur; float4 w_cur;
    if (e < e1) load_grp(ei, ew, E, e, e1, vec, c_cur, w_cur);
    while (e < e1) {
        const int en = e + estep;
        int4 c_nxt; float4 w_nxt;
        if (en < e1) load_grp(ei, ew, E, en, e1, vec, c_nxt, w_nxt);
#pragma unroll
        for (int i = 0; i < 4; ++i) {
            int c = ((const int*)&c_cur)[i];
            unsigned rc = (unsigned)(c - r0);
            if (rc < (unsigned)rcnt) {
                float wv = ((const float*)&w_cur)[i];
                unsigned wfix = (unsigned)(wv * FIX_SCALE + 0.5f);
                unsigned long long old =
                    atomicAdd(&hlds[rc], (1ULL << 32) | (unsigned long long)wfix);
                rank[e + i] = (int)(old >> 32);
            }
        }
        e = en;
        c_cur = c_nxt; w_cur = w_nxt;
    }
    __syncthreads();

    unsigned long long* dst = part + (size_t)s * N + r0;
    for (int i = t; i < rcnt; i += 256) dst[i] = hlds[i];
}

// --------------------------------------------- 2-phase exclusive scan ------
// Folds the NSLICE partials per node: deg = sum of fixed-point parts
// (+1 self loop), cnt = total count, base16[s][node] = exclusive prefix of
// per-slice counts (for CSR slot reconstruction).
__global__ __launch_bounds__(256) void scan_reduce(const unsigned long long* __restrict__ part,
                                                   float* __restrict__ dinv,
                                                   int* __restrict__ cnt,
                                                   unsigned short* __restrict__ base16,
                                                   int* __restrict__ blockSum, int N) {
    __shared__ int sred[256];
    const int t = threadIdx.x;
    const int i = blockIdx.x * 256 + t;
    int v = 0;
    if (i < N) {
        unsigned run = 0;
        unsigned wsum = 0;
#pragma unroll
        for (int s = 0; s < NSLICE; ++s) {
            unsigned long long p = part[(size_t)s * N + i];
            base16[(size_t)s * N + i] = (unsigned short)run;
            run += (unsigned)(p >> 32);
            wsum += (unsigned)p;
        }
        float d = (float)wsum * FIX_INV + 1.0f;   // +1 self-loop
        dinv[i] = rsqrtf(d);
        v = (int)run;
        cnt[i] = v;
    }
    sred[t] = v;
    __syncthreads();
#pragma unroll
    for (int off = 128; off > 0; off >>= 1) {
        if (t < off) sred[t] += sred[t + off];
        __syncthreads();
    }
    if (t == 0) blockSum[blockIdx.x] = sred[0];
}

__global__ __launch_bounds__(256) void scan_apply(const int* __restrict__ cnt,
                                                  const int* __restrict__ blockSum,
                                                  int* __restrict__ row_ptr, int N, int B) {
    __shared__ int bs[256];
    __shared__ int s[256];
    const int t = threadIdx.x;
    bs[t] = (t < B) ? blockSum[t] : 0;
    __syncthreads();
#pragma unroll
    for (int off = 1; off < 256; off <<= 1) {
        int u = (t >= off) ? bs[t - off] : 0;
        __syncthreads();
        bs[t] += u;
        __syncthreads();
    }
    const int myOff = (blockIdx.x > 0) ? bs[blockIdx.x - 1] : 0;
    const int i = blockIdx.x * 256 + t;
    const int v = (i < N) ? cnt[i] : 0;
    s[t] = v;
    __syncthreads();
#pragma unroll
    for (int off = 1; off < 256; off <<= 1) {
        int u = (t >= off) ? s[t - off] : 0;
        __syncthreads();
        s[t] += u;
        __syncthreads();
    }
    if (i < N) row_ptr[i] = s[t] - v + myOff;
    if (blockIdx.x == 0 && t == 0) row_ptr[N] = bs[B - 1];
}

// ------------------------------------------------- bucket fill (CSR) -------
__global__ void fill_kernel(const int* __restrict__ ei, const float* __restrict__ ew,
                            const float* __restrict__ dinv,
                            const int* __restrict__ row_ptr, const int* __restrict__ rank,
                            const unsigned short* __restrict__ base16,
                            int2* __restrict__ pairs, int E, int N, int SE) {
    int e = blockIdx.x * blockDim.x + threadIdx.x;
    if (e < E) {
        int r = ei[e];
        int c = ei[E + e];
        float w = dinv[r] * ew[e] * dinv[c];
        int s = e / SE;
        int slot = row_ptr[c] + (int)base16[(size_t)s * N + c] + rank[e];
        pairs[slot] = make_int2(r, __float_as_int(w));
    }
}

// ------------------------- fused aggregate + epilogue + NEXT-LAYER gemm ----
// Gather/scale/bias/relu; post-ReLU rows staged in LDS; block-local MFMA gemm
// produces the next layer's linear output (fp16 A/B, fp32 acc).
template <int DIN, int DOUT>
__global__ __launch_bounds__(256) void agg_gemm_kernel(
        const _Float16* __restrict__ H, const int* __restrict__ row_ptr,
        const int2* __restrict__ pairs, const float* __restrict__ dinv,
        const float* __restrict__ bias, const float* __restrict__ W,
        _Float16* __restrict__ Hout, int N) {
    constexpr int TPN = DIN / 8;      // threads per node
    constexpr int NPB = 256 / TPN;    // nodes per block
    constexpr int NC  = DIN / 32;     // gemm k-chunks
    constexpr int S   = NPB / 16;     // 16-row slabs per block
    constexpr int T   = DOUT / 16;    // 16-col tiles
    static_assert(S * T == 4, "one tile per wave");
    __shared__ _Float16 sA[NPB][DIN + 8];

    const int tid = threadIdx.x;
    const int g = tid / TPN;
    const int sl = tid % TPN;
    const int node0 = blockIdx.x * NPB;
    const int node = node0 + g;
    const bool valid = node < N;

    // ---- hoisted B-frags (fp32 W, loop-invariant; loads hide under gather) --
    const int w = tid >> 6;
    const int lane = tid & 63;
    const int q = lane >> 4;
    const int m = lane & 15;
    const int s = w & (S - 1);
    const int t = w / S;
    half8 bf[NC];
#pragma unroll
    for (int c = 0; c < NC; ++c) {
#pragma unroll
        for (int j = 0; j < 8; ++j)
            bf[c][j] = (_Float16)W[(size_t)(c * 32 + q * 8 + j) * DOUT + t * 16 + m];
    }

    float acc[8];
#pragma unroll
    for (int j = 0; j < 8; ++j) acc[j] = 0.0f;

    int beg = 0, end = 0;
    if (valid) { beg = row_ptr[node]; end = row_ptr[node + 1]; }

    if (end > beg) {
        const int last = end - 1;
        int2 p0 = pairs[beg];
        int2 p1 = pairs[min(beg + 1, last)];
        int2 p2 = pairs[min(beg + 2, last)];
        half8 u0 = *(const half8*)&H[(size_t)p0.x * DIN + sl * 8];
        half8 u1 = *(const half8*)&H[(size_t)p1.x * DIN + sl * 8];
        for (int k = beg; k < end; ++k) {
            int2 p3 = pairs[min(k + 3, last)];
            half8 u2 = *(const half8*)&H[(size_t)p2.x * DIN + sl * 8];
            float wv = __int_as_float(p0.y);
#pragma unroll
            for (int j = 0; j < 8; ++j) acc[j] = fmaf(wv, (float)u0[j], acc[j]);
            p0 = p1; p1 = p2; p2 = p3;
            u0 = u1; u1 = u2;
        }
    }

    if (valid) {
        // self-loop + bias + relu -> LDS (this IS the out row, fp16)
        float di = dinv[node];
        float d2 = di * di;
        half8 u = *(const half8*)&H[(size_t)node * DIN + sl * 8];
#pragma unroll
        for (int j = 0; j < 8; ++j) acc[j] = fmaf(d2, (float)u[j], acc[j]);
        float bb[8];
        *(float4*)&bb[0] = *(const float4*)&bias[sl * 8];
        *(float4*)&bb[4] = *(const float4*)&bias[sl * 8 + 4];
        half8 o;
#pragma unroll
        for (int j = 0; j < 8; ++j) o[j] = (_Float16)fmaxf(acc[j] + bb[j], 0.f);
        *(half8*)&sA[g][sl * 8] = o;
    }
    __syncthreads();

    // ---- next-layer gemm on the block's rows ----
    half8 a[NC];
#pragma unroll
    for (int c = 0; c < NC; ++c)
        a[c] = *(const half8*)&sA[s * 16 + m][c * 32 + q * 8];
    floatx4 o4 = (floatx4){0.f, 0.f, 0.f, 0.f};
#pragma unroll
    for (int c = 0; c < NC; ++c)
        o4 = __builtin_amdgcn_mfma_f32_16x16x32_f16(a[c], bf[c], o4, 0, 0, 0);
#pragma unroll
    for (int r = 0; r < 4; ++r) {
        const int nr = node0 + s * 16 + q * 4 + r;
        if (nr < N) Hout[(size_t)nr * DOUT + t * 16 + m] = (_Float16)o4[r];
    }
}

// -------------------------------------- final aggregate + epilogue (fp32) --
template <int D, typename OUT>
__global__ __launch_bounds__(256) void agg_kernel(const _Float16* __restrict__ H,
                                                  const int* __restrict__ row_ptr,
                                                  const int2* __restrict__ pairs,
                                                  const float* __restrict__ dinv,
                                                  const float* __restrict__ bias,
                                                  OUT* __restrict__ out, int N) {
    constexpr int TPN = D / 8;
    constexpr int NPB = 256 / TPN;
    const int tid = threadIdx.x;
    const int g = tid / TPN;
    const int lane = tid % TPN;
    const int node = blockIdx.x * NPB + g;
    if (node >= N) return;

    const int beg = row_ptr[node];
    const int end = row_ptr[node + 1];
    float acc[8];
#pragma unroll
    for (int j = 0; j < 8; ++j) acc[j] = 0.0f;

    if (end > beg) {
        const int last = end - 1;
        int2 p0 = pairs[beg];
        int2 p1 = pairs[min(beg + 1, last)];
        int2 p2 = pairs[min(beg + 2, last)];
        half8 u0 = *(const half8*)&H[(size_t)p0.x * D + lane * 8];
        half8 u1 = *(const half8*)&H[(size_t)p1.x * D + lane * 8];
        for (int k = beg; k < end; ++k) {
            int2 p3 = pairs[min(k + 3, last)];
            half8 u2 = *(const half8*)&H[(size_t)p2.x * D + lane * 8];
            float w = __int_as_float(p0.y);
#pragma unroll
            for (int j = 0; j < 8; ++j) acc[j] = fmaf(w, (float)u0[j], acc[j]);
            p0 = p1; p1 = p2; p2 = p3;
            u0 = u1; u1 = u2;
        }
    }
    float di = dinv[node];
    float d2 = di * di;
    {
        half8 u = *(const half8*)&H[(size_t)node * D + lane * 8];
#pragma unroll
        for (int j = 0; j < 8; ++j) acc[j] = fmaf(d2, (float)u[j], acc[j]);
    }
    float b[8];
    *(float4*)&b[0] = *(const float4*)&bias[lane * 8];
    *(float4*)&b[4] = *(const float4*)&bias[lane * 8 + 4];
#pragma unroll
    for (int j = 0; j < 8; ++j) acc[j] = fmaxf(acc[j] + b[j], 0.f);

    if constexpr (sizeof(OUT) == 2) {
        half8 o;
#pragma unroll
        for (int j = 0; j < 8; ++j) o[j] = (_Float16)acc[j];
        *(half8*)&out[(size_t)node * D + lane * 8] = o;
    } else {
        float* dst = (float*)&out[(size_t)node * D + lane * 8];
        *(float4*)&dst[0] = make_float4(acc[0], acc[1], acc[2], acc[3]);
        *(float4*)&dst[4] = make_float4(acc[4], acc[5], acc[6], acc[7]);
    }
}

// ---------------------------------------------------------------- launch ----
extern "C" void kernel_launch(void* const* d_in, const int* in_sizes, int n_in,
                              void* d_out, int out_size, void* d_ws, size_t ws_size,
                              hipStream_t stream) {
    const float* x   = (const float*)d_in[0];
    const int* ei    = (const int*)d_in[1];
    const float* ew  = (const float*)d_in[2];
    const float* W1  = (const float*)d_in[3];
    const float* b1  = (const float*)d_in[4];
    const float* W2  = (const float*)d_in[5];
    const float* b2  = (const float*)d_in[6];
    const float* W3  = (const float*)d_in[7];
    const float* b3  = (const float*)d_in[8];
    float* out = (float*)d_out;

    const int N = in_sizes[0] / D0;   // 50000
    const int E = in_sizes[2];        // 800000
    (void)n_in; (void)out_size; (void)ws_size;

    // ---- workspace carving ----
    char* ws = (char*)d_ws;
    size_t off = 0;
    auto carve = [&](size_t bytes) -> void* {
        void* p = (void*)(ws + off);
        off += (bytes + 255) & ~(size_t)255;
        return p;
    };
    float* dinv    = (float*)carve((size_t)N * 4);
    int*   cnt     = (int*)carve((size_t)N * 4);
    int*   row_ptr = (int*)carve((size_t)(N + 1) * 4);
    int*   rank    = (int*)carve((size_t)E * 4);
    int*   bsum    = (int*)carve(256 * 4);
    unsigned short* base16 = (unsigned short*)carve((size_t)N * NSLICE * 2);
    int2*  pairs   = (int2*)carve((size_t)E * 8);
    _Float16* bufH = (_Float16*)carve((size_t)N * D1 * 2);
    // part (N*NSLICE*8 = 12.8MB) aliases bufO (N*D1*2 = 12.8MB): part is dead
    // after scan_reduce; h2 is written later (agg_gemm1).
    size_t unionBytes = (size_t)N * NSLICE * 8;
    if ((size_t)N * D1 * 2 > unionBytes) unionBytes = (size_t)N * D1 * 2;
    char* uni = (char*)carve(unionBytes);
    unsigned long long* part = (unsigned long long*)uni;
    _Float16* bufO = (_Float16*)uni;

    _Float16* h1 = bufH;              // N x 128 fp16 (gemm1 out)
    _Float16* h2 = bufO;              // N x 64  fp16 (agg1+gemm2 out)
    _Float16* h3 = bufH;              // N x 32  fp16 (agg2+gemm3 out; h1 dead)

    const int eb = (E + 255) / 256;       // 3125
    const int scanB = (N + 255) / 256;    // 196 (must be <= 256)
    const int hB = NRANGE * NSLICE;       // 512 histogram blocks (25KB LDS each)
    const int gB = 768;                   // gemm blocks (3072 waves)
    const int SE = (((E + NSLICE - 1) / NSLICE) + 3) & ~3;   // mult of 4

    // ---- fused: LDS histogram + gemm1 (independent, one dispatch) ----
    hist_gemm1_kernel<<<hB + gB, 256, 0, stream>>>(
        x, W1, h1, N, ei, ew, part, rank, E, hB, gB, SE);

    // ---- CSR build ----
    scan_reduce<<<scanB, 256, 0, stream>>>(part, dinv, cnt, base16, bsum, N);
    scan_apply<<<scanB, 256, 0, stream>>>(cnt, bsum, row_ptr, N, scanB);
    fill_kernel<<<eb, 256, 0, stream>>>(ei, ew, dinv, row_ptr, rank, base16, pairs, E, N, SE);

    // ---- layer 1 aggregate (+ fused gemm2: 128 -> 64) ----
    agg_gemm_kernel<D1, D2><<<(N + 15) / 16, 256, 0, stream>>>(
        h1, row_ptr, pairs, dinv, b1, W2, h2, N);

    // ---- layer 2 aggregate (+ fused gemm3: 64 -> 32) ----
    agg_gemm_kernel<D2, D3><<<(N + 31) / 32, 256, 0, stream>>>(
        h2, row_ptr, pairs, dinv, b2, W3, h3, N);

    // ---- layer 3 aggregate + epilogue (fp32 out) ----
    agg_kernel<D3, float><<<(N + 63) / 64, 256, 0, stream>>>(
        h3, row_ptr, pairs, dinv, b3, out, N);
}

// Round 4
// 263.039 us; speedup vs baseline: 1.0484x; 1.0157x over previous
//
#include <hip/hip_runtime.h>
#include <hip/hip_fp16.h>

// GCN encoder: 3x (GCNConv + ReLU), dims 256->128->64->32
// N=50000 nodes, E=800000 edges. edge_index delivered as int32 (harness).
// R2: CSR gather.  R3/R11: multi-block scan, fused.  R5: fp16 H buffers.
// R6: MFMA gemms.  R7: atomic-free fill via rank.  R10: persistent-B gemm.
// R12: gemm1 fused INTO the histogram kernel (rides under the atomic wall).
// R13: gemm2/gemm3 fused into agg1/agg2 epilogues (LDS-staged MFMA).
// R14/R15: LDS-histogram variants measured SLOWER (80-106us vs 66us) --
//      reverted to the device-atomic packed histogram (measured 12 G/s wall,
//      66us, replication-invariant; gemm1 hides under it for free).
// R16: agg chain is the real target (~180us of random 256B row gathers,
//      latency-bound: only 2 rows in flight vs ~600-900cy remote latency).
//      Deepened software pipeline: 4 rows + 6 pairs in flight; self-row,
//      bias, dinv loads hoisted ahead of the edge loop.

#define D0 256
#define D1 128
#define D2 64
#define D3 32

#define FIX_SCALE 16777216.0f           // 2^24 fixed-point for degree
#define FIX_INV   (1.0f / 16777216.0f)

typedef _Float16 half8 __attribute__((ext_vector_type(8)));
typedef float floatx4 __attribute__((ext_vector_type(4)));

// ------------------------------------------------------ gemm device core ---
// H[N,BN] (fp16) = X[N,K] @ W[K,BN] (both possibly fp32, cvt in-register).
// A[m=lane&15][k=quad*8+j]; B[k][n]; D row=quad*4+reg.
template <typename SRC>
__device__ __forceinline__ half8 loadA(const SRC* __restrict__ p) {
    if constexpr (sizeof(SRC) == 4) {
        float4 f0 = *(const float4*)p;
        float4 f1 = *(const float4*)(p + 4);
        half8 v;
        v[0] = (_Float16)f0.x; v[1] = (_Float16)f0.y;
        v[2] = (_Float16)f0.z; v[3] = (_Float16)f0.w;
        v[4] = (_Float16)f1.x; v[5] = (_Float16)f1.y;
        v[6] = (_Float16)f1.z; v[7] = (_Float16)f1.w;
        return v;
    } else {
        return *(const half8*)p;
    }
}

template <int K, int BN, typename SRC>
__device__ __forceinline__ void gemm_work(const SRC* __restrict__ X,
                                          const float* __restrict__ W,
                                          _Float16* __restrict__ H, int N,
                                          int w, int totalWaves) {
    constexpr int NC = K / 32;        // k-chunks
    constexpr int CG = BN / 32;       // col groups (waves per slab)
    const int lane = threadIdx.x & 63;
    const int quad = lane >> 4;
    const int m = lane & 15;
    const int cg = w & (CG - 1);
    const int nslab = N >> 4;         // N multiple of 16
    const int stride = totalWaves / CG;
    int slab = w / CG;
    if (slab >= nslab) return;
    const int n0 = cg * 32;

    // ---- persistent B-frags: W fp32, strided, loaded once per wave ----
    half8 b0[NC], b1[NC];
#pragma unroll
    for (int c = 0; c < NC; ++c) {
#pragma unroll
        for (int j = 0; j < 8; ++j) {
            int k = c * 32 + quad * 8 + j;
            b0[c][j] = (_Float16)W[(size_t)k * BN + n0 + m];
            b1[c][j] = (_Float16)W[(size_t)k * BN + n0 + 16 + m];
        }
    }

    half8 a[NC];
#pragma unroll
    for (int c = 0; c < NC; ++c)
        a[c] = loadA(&X[(size_t)(slab * 16 + m) * K + c * 32 + quad * 8]);

    while (true) {
        const int next = slab + stride;
        half8 an[NC];
        if (next < nslab) {
#pragma unroll
            for (int c = 0; c < NC; ++c)
                an[c] = loadA(&X[(size_t)(next * 16 + m) * K + c * 32 + quad * 8]);
        }

        floatx4 acc0 = (floatx4){0.f, 0.f, 0.f, 0.f};
        floatx4 acc1 = (floatx4){0.f, 0.f, 0.f, 0.f};
#pragma unroll
        for (int c = 0; c < NC; ++c) {
            acc0 = __builtin_amdgcn_mfma_f32_16x16x32_f16(a[c], b0[c], acc0, 0, 0, 0);
            acc1 = __builtin_amdgcn_mfma_f32_16x16x32_f16(a[c], b1[c], acc1, 0, 0, 0);
        }

        const int r0 = slab * 16 + quad * 4;
#pragma unroll
        for (int r = 0; r < 4; ++r) {
            H[(size_t)(r0 + r) * BN + n0 + m]      = (_Float16)acc0[r];
            H[(size_t)(r0 + r) * BN + n0 + 16 + m] = (_Float16)acc1[r];
        }

        if (next >= nslab) break;
        slab = next;
#pragma unroll
        for (int c = 0; c < NC; ++c) a[c] = an[c];
    }
}

// ------------------------------- fused histogram + gemm1 (independent) -----
// Blocks [0,gB): gemm1 (x fp32 @ W1 fp32 -> h1 fp16).
// Blocks [gB,..): packed deg+cnt device atomic; old>>32 = edge rank.
// Measured: this atomic wall is ~66us at 12 G atomics/s and is invariant to
// address replication; gemm1 co-schedules under it for free.
__global__ __launch_bounds__(256) void hist_gemm1_kernel(
        const float* __restrict__ x, const float* __restrict__ W1,
        _Float16* __restrict__ h1, int N,
        const int* __restrict__ ei, const float* __restrict__ ew,
        unsigned long long* __restrict__ pk, int* __restrict__ rank, int E,
        int gB) {
    const int b = blockIdx.x;
    if (b < gB) {
        gemm_work<D0, D1, float>(x, W1, h1, N, b * 4 + (threadIdx.x >> 6), gB * 4);
    } else {
        int e = (b - gB) * 256 + threadIdx.x;
        if (e < E) {
            int c = ei[E + e];
            unsigned int wfix = (unsigned int)(ew[e] * FIX_SCALE + 0.5f);
            unsigned long long old =
                atomicAdd(&pk[c], (1ULL << 32) | (unsigned long long)wfix);
            rank[e] = (int)(old >> 32);
        }
    }
}

// --------------------------------------------- 2-phase exclusive scan ------
__global__ __launch_bounds__(256) void scan_reduce(const unsigned long long* __restrict__ pk,
                                                   float* __restrict__ dinv,
                                                   int* __restrict__ cnt,
                                                   int* __restrict__ blockSum, int N) {
    __shared__ int s[256];
    const int t = threadIdx.x;
    const int i = blockIdx.x * 256 + t;
    int v = 0;
    if (i < N) {
        unsigned long long p = pk[i];
        float d = (float)(unsigned int)(p & 0xffffffffULL) * FIX_INV + 1.0f;  // +1 self-loop
        dinv[i] = rsqrtf(d);
        v = (int)(p >> 32);
        cnt[i] = v;
    }
    s[t] = v;
    __syncthreads();
#pragma unroll
    for (int off = 128; off > 0; off >>= 1) {
        if (t < off) s[t] += s[t + off];
        __syncthreads();
    }
    if (t == 0) blockSum[blockIdx.x] = s[0];
}

__global__ __launch_bounds__(256) void scan_apply(const int* __restrict__ cnt,
                                                  const int* __restrict__ blockSum,
                                                  int* __restrict__ row_ptr, int N, int B) {
    __shared__ int bs[256];
    __shared__ int s[256];
    const int t = threadIdx.x;
    bs[t] = (t < B) ? blockSum[t] : 0;
    __syncthreads();
#pragma unroll
    for (int off = 1; off < 256; off <<= 1) {
        int u = (t >= off) ? bs[t - off] : 0;
        __syncthreads();
        bs[t] += u;
        __syncthreads();
    }
    const int myOff = (blockIdx.x > 0) ? bs[blockIdx.x - 1] : 0;
    const int i = blockIdx.x * 256 + t;
    const int v = (i < N) ? cnt[i] : 0;
    s[t] = v;
    __syncthreads();
#pragma unroll
    for (int off = 1; off < 256; off <<= 1) {
        int u = (t >= off) ? s[t - off] : 0;
        __syncthreads();
        s[t] += u;
        __syncthreads();
    }
    if (i < N) row_ptr[i] = s[t] - v + myOff;
    if (blockIdx.x == 0 && t == 0) row_ptr[N] = bs[B - 1];
}

// ------------------------------------------------- bucket fill (CSR) -------
__global__ void fill_kernel(const int* __restrict__ ei, const float* __restrict__ ew,
                            const float* __restrict__ dinv,
                            const int* __restrict__ row_ptr, const int* __restrict__ rank,
                            int2* __restrict__ pairs, int E) {
    int e = blockIdx.x * blockDim.x + threadIdx.x;
    if (e < E) {
        int r = ei[e];
        int c = ei[E + e];
        float w = dinv[r] * ew[e] * dinv[c];
        pairs[row_ptr[c] + rank[e]] = make_int2(r, __float_as_int(w));
    }
}

// ------------------------- fused aggregate + epilogue + NEXT-LAYER gemm ----
// Gather/scale/bias/relu; post-ReLU rows staged in LDS; block-local MFMA gemm
// produces the next layer's linear output (fp16 A/B, fp32 acc).
// R16: 4 rows + 6 pairs in flight; self-row/bias/dinv hoisted.
template <int DIN, int DOUT>
__global__ __launch_bounds__(256) void agg_gemm_kernel(
        const _Float16* __restrict__ H, const int* __restrict__ row_ptr,
        const int2* __restrict__ pairs, const float* __restrict__ dinv,
        const float* __restrict__ bias, const float* __restrict__ W,
        _Float16* __restrict__ Hout, int N) {
    constexpr int TPN = DIN / 8;      // threads per node
    constexpr int NPB = 256 / TPN;    // nodes per block
    constexpr int NC  = DIN / 32;     // gemm k-chunks
    constexpr int S   = NPB / 16;     // 16-row slabs per block
    constexpr int T   = DOUT / 16;    // 16-col tiles
    static_assert(S * T == 4, "one tile per wave");
    __shared__ _Float16 sA[NPB][DIN + 8];

    const int tid = threadIdx.x;
    const int g = tid / TPN;
    const int sl = tid % TPN;
    const int node0 = blockIdx.x * NPB;
    const int node = node0 + g;
    const bool valid = node < N;

    // ---- hoisted B-frags (fp32 W, loop-invariant; loads hide under gather) --
    const int w = tid >> 6;
    const int lane = tid & 63;
    const int q = lane >> 4;
    const int m = lane & 15;
    const int s = w & (S - 1);
    const int t = w / S;
    half8 bf[NC];
#pragma unroll
    for (int c = 0; c < NC; ++c) {
#pragma unroll
        for (int j = 0; j < 8; ++j)
            bf[c][j] = (_Float16)W[(size_t)(c * 32 + q * 8 + j) * DOUT + t * 16 + m];
    }

    float acc[8];
#pragma unroll
    for (int j = 0; j < 8; ++j) acc[j] = 0.0f;

    int beg = 0, end = 0;
    float di = 0.f;
    half8 uself = (half8){0,0,0,0,0,0,0,0};
    float bb[8];
    if (valid) {
        beg = row_ptr[node];
        end = row_ptr[node + 1];
        di = dinv[node];                                  // early issue
        uself = *(const half8*)&H[(size_t)node * DIN + sl * 8];  // early issue
        *(float4*)&bb[0] = *(const float4*)&bias[sl * 8];
        *(float4*)&bb[4] = *(const float4*)&bias[sl * 8 + 4];
    }

    if (end > beg) {
        const int last = end - 1;
        // 6 pairs / 4 rows in flight
        int2 p0 = pairs[beg];
        int2 p1 = pairs[min(beg + 1, last)];
        int2 p2 = pairs[min(beg + 2, last)];
        int2 p3 = pairs[min(beg + 3, last)];
        int2 p4 = pairs[min(beg + 4, last)];
        half8 u0 = *(const half8*)&H[(size_t)p0.x * DIN + sl * 8];
        half8 u1 = *(const half8*)&H[(size_t)p1.x * DIN + sl * 8];
        half8 u2 = *(const half8*)&H[(size_t)p2.x * DIN + sl * 8];
        half8 u3 = *(const half8*)&H[(size_t)p3.x * DIN + sl * 8];
        for (int k = beg; k < end; ++k) {
            int2 p5 = pairs[min(k + 5, last)];
            half8 u4 = *(const half8*)&H[(size_t)p4.x * DIN + sl * 8];
            float wv = __int_as_float(p0.y);
#pragma unroll
            for (int j = 0; j < 8; ++j) acc[j] = fmaf(wv, (float)u0[j], acc[j]);
            p0 = p1; p1 = p2; p2 = p3; p3 = p4; p4 = p5;
            u0 = u1; u1 = u2; u2 = u3; u3 = u4;
        }
    }

    if (valid) {
        // self-loop + bias + relu -> LDS (this IS the out row, fp16)
        float d2 = di * di;
#pragma unroll
        for (int j = 0; j < 8; ++j) acc[j] = fmaf(d2, (float)uself[j], acc[j]);
        half8 o;
#pragma unroll
        for (int j = 0; j < 8; ++j) o[j] = (_Float16)fmaxf(acc[j] + bb[j], 0.f);
        *(half8*)&sA[g][sl * 8] = o;
    }
    __syncthreads();

    // ---- next-layer gemm on the block's rows ----
    half8 a[NC];
#pragma unroll
    for (int c = 0; c < NC; ++c)
        a[c] = *(const half8*)&sA[s * 16 + m][c * 32 + q * 8];
    floatx4 o4 = (floatx4){0.f, 0.f, 0.f, 0.f};
#pragma unroll
    for (int c = 0; c < NC; ++c)
        o4 = __builtin_amdgcn_mfma_f32_16x16x32_f16(a[c], bf[c], o4, 0, 0, 0);
#pragma unroll
    for (int r = 0; r < 4; ++r) {
        const int nr = node0 + s * 16 + q * 4 + r;
        if (nr < N) Hout[(size_t)nr * DOUT + t * 16 + m] = (_Float16)o4[r];
    }
}

// -------------------------------------- final aggregate + epilogue (fp32) --
template <int D, typename OUT>
__global__ __launch_bounds__(256) void agg_kernel(const _Float16* __restrict__ H,
                                                  const int* __restrict__ row_ptr,
                                                  const int2* __restrict__ pairs,
                                                  const float* __restrict__ dinv,
                                                  const float* __restrict__ bias,
                                                  OUT* __restrict__ out, int N) {
    constexpr int TPN = D / 8;
    constexpr int NPB = 256 / TPN;
    const int tid = threadIdx.x;
    const int g = tid / TPN;
    const int lane = tid % TPN;
    const int node = blockIdx.x * NPB + g;
    if (node >= N) return;

    const int beg = row_ptr[node];
    const int end = row_ptr[node + 1];
    const float di = dinv[node];                                   // early
    const half8 uself = *(const half8*)&H[(size_t)node * D + lane * 8];  // early
    float b[8];
    *(float4*)&b[0] = *(const float4*)&bias[lane * 8];
    *(float4*)&b[4] = *(const float4*)&bias[lane * 8 + 4];

    float acc[8];
#pragma unroll
    for (int j = 0; j < 8; ++j) acc[j] = 0.0f;

    if (end > beg) {
        const int last = end - 1;
        int2 p0 = pairs[beg];
        int2 p1 = pairs[min(beg + 1, last)];
        int2 p2 = pairs[min(beg + 2, last)];
        int2 p3 = pairs[min(beg + 3, last)];
        int2 p4 = pairs[min(beg + 4, last)];
        half8 u0 = *(const half8*)&H[(size_t)p0.x * D + lane * 8];
        half8 u1 = *(const half8*)&H[(size_t)p1.x * D + lane * 8];
        half8 u2 = *(const half8*)&H[(size_t)p2.x * D + lane * 8];
        half8 u3 = *(const half8*)&H[(size_t)p3.x * D + lane * 8];
        for (int k = beg; k < end; ++k) {
            int2 p5 = pairs[min(k + 5, last)];
            half8 u4 = *(const half8*)&H[(size_t)p4.x * D + lane * 8];
            float w = __int_as_float(p0.y);
#pragma unroll
            for (int j = 0; j < 8; ++j) acc[j] = fmaf(w, (float)u0[j], acc[j]);
            p0 = p1; p1 = p2; p2 = p3; p3 = p4; p4 = p5;
            u0 = u1; u1 = u2; u2 = u3; u3 = u4;
        }
    }
    const float d2 = di * di;
#pragma unroll
    for (int j = 0; j < 8; ++j) acc[j] = fmaf(d2, (float)uself[j], acc[j]);
#pragma unroll
    for (int j = 0; j < 8; ++j) acc[j] = fmaxf(acc[j] + b[j], 0.f);

    if constexpr (sizeof(OUT) == 2) {
        half8 o;
#pragma unroll
        for (int j = 0; j < 8; ++j) o[j] = (_Float16)acc[j];
        *(half8*)&out[(size_t)node * D + lane * 8] = o;
    } else {
        float* dst = (float*)&out[(size_t)node * D + lane * 8];
        *(float4*)&dst[0] = make_float4(acc[0], acc[1], acc[2], acc[3]);
        *(float4*)&dst[4] = make_float4(acc[4], acc[5], acc[6], acc[7]);
    }
}

// ---------------------------------------------------------------- launch ----
extern "C" void kernel_launch(void* const* d_in, const int* in_sizes, int n_in,
                              void* d_out, int out_size, void* d_ws, size_t ws_size,
                              hipStream_t stream) {
    const float* x   = (const float*)d_in[0];
    const int* ei    = (const int*)d_in[1];
    const float* ew  = (const float*)d_in[2];
    const float* W1  = (const float*)d_in[3];
    const float* b1  = (const float*)d_in[4];
    const float* W2  = (const float*)d_in[5];
    const float* b2  = (const float*)d_in[6];
    const float* W3  = (const float*)d_in[7];
    const float* b3  = (const float*)d_in[8];
    float* out = (float*)d_out;

    const int N = in_sizes[0] / D0;   // 50000
    const int E = in_sizes[2];        // 800000
    (void)n_in; (void)out_size; (void)ws_size;

    // ---- workspace carving ----
    char* ws = (char*)d_ws;
    size_t off = 0;
    auto carve = [&](size_t bytes) -> void* {
        void* p = (void*)(ws + off);
        off += (bytes + 255) & ~(size_t)255;
        return p;
    };
    unsigned long long* pk = (unsigned long long*)carve((size_t)N * 8);
    float* dinv    = (float*)carve((size_t)N * 4);
    int*   cnt     = (int*)carve((size_t)N * 4);
    int*   row_ptr = (int*)carve((size_t)(N + 1) * 4);
    int*   rank    = (int*)carve((size_t)E * 4);
    int*   bsum    = (int*)carve(256 * 4);
    int2*  pairs   = (int2*)carve((size_t)E * 8);
    _Float16* bufH = (_Float16*)carve((size_t)N * D1 * 2);
    _Float16* bufO = (_Float16*)carve((size_t)N * D1 * 2);

    _Float16* h1 = bufH;              // N x 128 fp16 (gemm1 out)
    _Float16* h2 = bufO;              // N x 64  fp16 (agg1+gemm2 out)
    _Float16* h3 = bufH;              // N x 32  fp16 (agg2+gemm3 out; h1 dead)

    const int eb = (E + 255) / 256;       // 3125
    const int scanB = (N + 255) / 256;    // 196 (must be <= 256)
    const int gB = 768;                   // gemm blocks (3072 waves)

    // ---- fused: gemm1 + histogram (independent work, one dispatch) ----
    hipMemsetAsync(pk, 0, (size_t)N * 8, stream);
    hist_gemm1_kernel<<<gB + eb, 256, 0, stream>>>(
        x, W1, h1, N, ei, ew, pk, rank, E, gB);

    // ---- CSR build ----
    scan_reduce<<<scanB, 256, 0, stream>>>(pk, dinv, cnt, bsum, N);
    scan_apply<<<scanB, 256, 0, stream>>>(cnt, bsum, row_ptr, N, scanB);
    fill_kernel<<<eb, 256, 0, stream>>>(ei, ew, dinv, row_ptr, rank, pairs, E);

    // ---- layer 1 aggregate (+ fused gemm2: 128 -> 64) ----
    agg_gemm_kernel<D1, D2><<<(N + 15) / 16, 256, 0, stream>>>(
        h1, row_ptr, pairs, dinv, b1, W2, h2, N);

    // ---- layer 2 aggregate (+ fused gemm3: 64 -> 32) ----
    agg_gemm_kernel<D2, D3><<<(N + 31) / 32, 256, 0, stream>>>(
        h2, row_ptr, pairs, dinv, b2, W3, h3, N);

    // ---- layer 3 aggregate + epilogue (fp32 out) ----
    agg_kernel<D3, float><<<(N + 63) / 64, 256, 0, stream>>>(
        h3, row_ptr, pairs, dinv, b3, out, N);
}

// Round 5
// 253.942 us; speedup vs baseline: 1.0860x; 1.0358x over previous
//
#include <hip/hip_runtime.h>
#include <hip/hip_fp16.h>

// GCN encoder: 3x (GCNConv + ReLU), dims 256->128->64->32
// N=50000 nodes, E=800000 edges. edge_index delivered as int32 (harness).
// R2: CSR gather.  R3/R11: multi-block scan.  R5: fp16 H buffers.
// R6: MFMA gemms.  R7: atomic-free fill via rank.  R10: persistent-B gemm.
// R13: gemm2/gemm3 fused into agg1/agg2 epilogues (LDS-staged MFMA).
// R14/R15: LDS-histogram variants SLOWER (80-106us) -> device atomics kept.
// R16: agg pipeline depth 3->5 NEUTRAL -> agg is gather-throughput bound,
//      not latency bound.
// R17: "12G/s atomic wall" was never isolated -- evidence (R14: gB 768->512
//      => dispatch 66->90us, exactly 1.5x) points at GEMM1 as the long pole
//      of the fused dispatch. This round: hist standalone (counters reveal
//      its true cost); gemm1 rebuilt with LDS A-staging (slab staged once
//      per block, fp32->fp16 cvt once, double-buffered; A traffic = 51MB
//      exactly); gemm1 re-fused with fill_kernel (independent work).

#define D0 256
#define D1 128
#define D2 64
#define D3 32

#define FIX_SCALE 16777216.0f           // 2^24 fixed-point for degree
#define FIX_INV   (1.0f / 16777216.0f)

typedef _Float16 half8 __attribute__((ext_vector_type(8)));
typedef float floatx4 __attribute__((ext_vector_type(4)));

// ---------------------------------------------------- hist (standalone) ----
// Packed deg+cnt device atomic; old>>32 = edge rank.
__global__ __launch_bounds__(256) void hist_kernel(
        const int* __restrict__ ei, const float* __restrict__ ew,
        unsigned long long* __restrict__ pk, int* __restrict__ rank, int E) {
    int e = blockIdx.x * 256 + threadIdx.x;
    if (e < E) {
        int c = ei[E + e];
        unsigned int wfix = (unsigned int)(ew[e] * FIX_SCALE + 0.5f);
        unsigned long long old =
            atomicAdd(&pk[c], (1ULL << 32) | (unsigned long long)wfix);
        rank[e] = (int)(old >> 32);
    }
}

// --------------------------------------------- 2-phase exclusive scan ------
__global__ __launch_bounds__(256) void scan_reduce(const unsigned long long* __restrict__ pk,
                                                   float* __restrict__ dinv,
                                                   int* __restrict__ cnt,
                                                   int* __restrict__ blockSum, int N) {
    __shared__ int s[256];
    const int t = threadIdx.x;
    const int i = blockIdx.x * 256 + t;
    int v = 0;
    if (i < N) {
        unsigned long long p = pk[i];
        float d = (float)(unsigned int)(p & 0xffffffffULL) * FIX_INV + 1.0f;  // +1 self-loop
        dinv[i] = rsqrtf(d);
        v = (int)(p >> 32);
        cnt[i] = v;
    }
    s[t] = v;
    __syncthreads();
#pragma unroll
    for (int off = 128; off > 0; off >>= 1) {
        if (t < off) s[t] += s[t + off];
        __syncthreads();
    }
    if (t == 0) blockSum[blockIdx.x] = s[0];
}

__global__ __launch_bounds__(256) void scan_apply(const int* __restrict__ cnt,
                                                  const int* __restrict__ blockSum,
                                                  int* __restrict__ row_ptr, int N, int B) {
    __shared__ int bs[256];
    __shared__ int s[256];
    const int t = threadIdx.x;
    bs[t] = (t < B) ? blockSum[t] : 0;
    __syncthreads();
#pragma unroll
    for (int off = 1; off < 256; off <<= 1) {
        int u = (t >= off) ? bs[t - off] : 0;
        __syncthreads();
        bs[t] += u;
        __syncthreads();
    }
    const int myOff = (blockIdx.x > 0) ? bs[blockIdx.x - 1] : 0;
    const int i = blockIdx.x * 256 + t;
    const int v = (i < N) ? cnt[i] : 0;
    s[t] = v;
    __syncthreads();
#pragma unroll
    for (int off = 1; off < 256; off <<= 1) {
        int u = (t >= off) ? s[t - off] : 0;
        __syncthreads();
        s[t] += u;
        __syncthreads();
    }
    if (i < N) row_ptr[i] = s[t] - v + myOff;
    if (blockIdx.x == 0 && t == 0) row_ptr[N] = bs[B - 1];
}

// ------------------------------------ gemm1: LDS-staged A, persistent B ----
// Block = 4 waves = 4 col groups of one 16-row slab. Slab staged to LDS once
// (fp32 -> fp16 cvt once), double-buffered. Row pad +8 halves: 528B stride
// (16B aligned, 2-way bank alias = free).
__device__ __forceinline__ void stage_slab(const float* __restrict__ X, int slab,
                                           _Float16 (*__restrict__ sA)[D0 + 8], int t) {
    const int row = t >> 4;
    const int c0 = (t & 15) * 16;
    const float* src = X + (size_t)(slab * 16 + row) * D0 + c0;
    float4 f0 = *(const float4*)(src + 0);
    float4 f1 = *(const float4*)(src + 4);
    float4 f2 = *(const float4*)(src + 8);
    float4 f3 = *(const float4*)(src + 12);
    half8 h0, h1;
    h0[0] = (_Float16)f0.x; h0[1] = (_Float16)f0.y;
    h0[2] = (_Float16)f0.z; h0[3] = (_Float16)f0.w;
    h0[4] = (_Float16)f1.x; h0[5] = (_Float16)f1.y;
    h0[6] = (_Float16)f1.z; h0[7] = (_Float16)f1.w;
    h1[0] = (_Float16)f2.x; h1[1] = (_Float16)f2.y;
    h1[2] = (_Float16)f2.z; h1[3] = (_Float16)f2.w;
    h1[4] = (_Float16)f3.x; h1[5] = (_Float16)f3.y;
    h1[6] = (_Float16)f3.z; h1[7] = (_Float16)f3.w;
    *(half8*)&sA[row][c0]     = h0;
    *(half8*)&sA[row][c0 + 8] = h1;
}

// -------------------------- fused fill + gemm1 (independent work) ----------
// Blocks [0,gB): gemm1 (x fp32 @ W1 fp32 -> h1 fp16), LDS-staged A.
// Blocks [gB,..): CSR bucket fill (needs row_ptr/rank/dinv, not h1).
__global__ __launch_bounds__(256) void fillgemm_kernel(
        const float* __restrict__ x, const float* __restrict__ W1,
        _Float16* __restrict__ h1, int N,
        const int* __restrict__ ei, const float* __restrict__ ew,
        const float* __restrict__ dinv, const int* __restrict__ row_ptr,
        const int* __restrict__ rank, int2* __restrict__ pairs, int E, int gB) {
    __shared__ _Float16 sA[2][16][D0 + 8];
    const int b = blockIdx.x;
    if (b >= gB) {
        int e = (b - gB) * 256 + threadIdx.x;
        if (e < E) {
            int r = ei[e];
            int c = ei[E + e];
            float w = dinv[r] * ew[e] * dinv[c];
            pairs[row_ptr[c] + rank[e]] = make_int2(r, __float_as_int(w));
        }
        return;
    }
    constexpr int NC = D0 / 32;       // 8 k-chunks
    const int tid = threadIdx.x;
    const int w = tid >> 6;
    const int lane = tid & 63;
    const int quad = lane >> 4;
    const int m = lane & 15;
    const int n0 = w * 32;            // wave = col group

    // ---- persistent B-frags (W1 fp32, loaded once per wave) ----
    half8 b0[NC], b1[NC];
#pragma unroll
    for (int c = 0; c < NC; ++c) {
#pragma unroll
        for (int j = 0; j < 8; ++j) {
            int k = c * 32 + quad * 8 + j;
            b0[c][j] = (_Float16)W1[(size_t)k * D1 + n0 + m];
            b1[c][j] = (_Float16)W1[(size_t)k * D1 + n0 + 16 + m];
        }
    }

    const int nslab = N >> 4;         // 3125
    int slab = b;
    if (slab >= nslab) return;
    stage_slab(x, slab, sA[0], tid);
    __syncthreads();
    int buf = 0;
    while (true) {
        const int next = slab + gB;
        if (next < nslab) stage_slab(x, next, sA[buf ^ 1], tid);

        half8 a[NC];
#pragma unroll
        for (int c = 0; c < NC; ++c)
            a[c] = *(const half8*)&sA[buf][m][c * 32 + quad * 8];
        floatx4 acc0 = (floatx4){0.f, 0.f, 0.f, 0.f};
        floatx4 acc1 = (floatx4){0.f, 0.f, 0.f, 0.f};
#pragma unroll
        for (int c = 0; c < NC; ++c) {
            acc0 = __builtin_amdgcn_mfma_f32_16x16x32_f16(a[c], b0[c], acc0, 0, 0, 0);
            acc1 = __builtin_amdgcn_mfma_f32_16x16x32_f16(a[c], b1[c], acc1, 0, 0, 0);
        }

        const int r0 = slab * 16 + quad * 4;
#pragma unroll
        for (int r = 0; r < 4; ++r) {
            h1[(size_t)(r0 + r) * D1 + n0 + m]      = (_Float16)acc0[r];
            h1[(size_t)(r0 + r) * D1 + n0 + 16 + m] = (_Float16)acc1[r];
        }
        __syncthreads();
        if (next >= nslab) break;
        slab = next;
        buf ^= 1;
    }
}

// ------------------------- fused aggregate + epilogue + NEXT-LAYER gemm ----
// Gather/scale/bias/relu; post-ReLU rows staged in LDS; block-local MFMA gemm
// produces the next layer's linear output (fp16 A/B, fp32 acc).
template <int DIN, int DOUT>
__global__ __launch_bounds__(256) void agg_gemm_kernel(
        const _Float16* __restrict__ H, const int* __restrict__ row_ptr,
        const int2* __restrict__ pairs, const float* __restrict__ dinv,
        const float* __restrict__ bias, const float* __restrict__ W,
        _Float16* __restrict__ Hout, int N) {
    constexpr int TPN = DIN / 8;      // threads per node
    constexpr int NPB = 256 / TPN;    // nodes per block
    constexpr int NC  = DIN / 32;     // gemm k-chunks
    constexpr int S   = NPB / 16;     // 16-row slabs per block
    constexpr int T   = DOUT / 16;    // 16-col tiles
    static_assert(S * T == 4, "one tile per wave");
    __shared__ _Float16 sA[NPB][DIN + 8];

    const int tid = threadIdx.x;
    const int g = tid / TPN;
    const int sl = tid % TPN;
    const int node0 = blockIdx.x * NPB;
    const int node = node0 + g;
    const bool valid = node < N;

    // ---- hoisted B-frags (fp32 W, loop-invariant; loads hide under gather) --
    const int w = tid >> 6;
    const int lane = tid & 63;
    const int q = lane >> 4;
    const int m = lane & 15;
    const int s = w & (S - 1);
    const int t = w / S;
    half8 bf[NC];
#pragma unroll
    for (int c = 0; c < NC; ++c) {
#pragma unroll
        for (int j = 0; j < 8; ++j)
            bf[c][j] = (_Float16)W[(size_t)(c * 32 + q * 8 + j) * DOUT + t * 16 + m];
    }

    float acc[8];
#pragma unroll
    for (int j = 0; j < 8; ++j) acc[j] = 0.0f;

    int beg = 0, end = 0;
    float di = 0.f;
    half8 uself = (half8){0,0,0,0,0,0,0,0};
    float bb[8];
    if (valid) {
        beg = row_ptr[node];
        end = row_ptr[node + 1];
        di = dinv[node];                                  // early issue
        uself = *(const half8*)&H[(size_t)node * DIN + sl * 8];  // early issue
        *(float4*)&bb[0] = *(const float4*)&bias[sl * 8];
        *(float4*)&bb[4] = *(const float4*)&bias[sl * 8 + 4];
    }

    if (end > beg) {
        const int last = end - 1;
        int2 p0 = pairs[beg];
        int2 p1 = pairs[min(beg + 1, last)];
        int2 p2 = pairs[min(beg + 2, last)];
        int2 p3 = pairs[min(beg + 3, last)];
        int2 p4 = pairs[min(beg + 4, last)];
        half8 u0 = *(const half8*)&H[(size_t)p0.x * DIN + sl * 8];
        half8 u1 = *(const half8*)&H[(size_t)p1.x * DIN + sl * 8];
        half8 u2 = *(const half8*)&H[(size_t)p2.x * DIN + sl * 8];
        half8 u3 = *(const half8*)&H[(size_t)p3.x * DIN + sl * 8];
        for (int k = beg; k < end; ++k) {
            int2 p5 = pairs[min(k + 5, last)];
            half8 u4 = *(const half8*)&H[(size_t)p4.x * DIN + sl * 8];
            float wv = __int_as_float(p0.y);
#pragma unroll
            for (int j = 0; j < 8; ++j) acc[j] = fmaf(wv, (float)u0[j], acc[j]);
            p0 = p1; p1 = p2; p2 = p3; p3 = p4; p4 = p5;
            u0 = u1; u1 = u2; u2 = u3; u3 = u4;
        }
    }

    if (valid) {
        // self-loop + bias + relu -> LDS (this IS the out row, fp16)
        float d2 = di * di;
#pragma unroll
        for (int j = 0; j < 8; ++j) acc[j] = fmaf(d2, (float)uself[j], acc[j]);
        half8 o;
#pragma unroll
        for (int j = 0; j < 8; ++j) o[j] = (_Float16)fmaxf(acc[j] + bb[j], 0.f);
        *(half8*)&sA[g][sl * 8] = o;
    }
    __syncthreads();

    // ---- next-layer gemm on the block's rows ----
    half8 a[NC];
#pragma unroll
    for (int c = 0; c < NC; ++c)
        a[c] = *(const half8*)&sA[s * 16 + m][c * 32 + q * 8];
    floatx4 o4 = (floatx4){0.f, 0.f, 0.f, 0.f};
#pragma unroll
    for (int c = 0; c < NC; ++c)
        o4 = __builtin_amdgcn_mfma_f32_16x16x32_f16(a[c], bf[c], o4, 0, 0, 0);
#pragma unroll
    for (int r = 0; r < 4; ++r) {
        const int nr = node0 + s * 16 + q * 4 + r;
        if (nr < N) Hout[(size_t)nr * DOUT + t * 16 + m] = (_Float16)o4[r];
    }
}

// -------------------------------------- final aggregate + epilogue (fp32) --
template <int D, typename OUT>
__global__ __launch_bounds__(256) void agg_kernel(const _Float16* __restrict__ H,
                                                  const int* __restrict__ row_ptr,
                                                  const int2* __restrict__ pairs,
                                                  const float* __restrict__ dinv,
                                                  const float* __restrict__ bias,
                                                  OUT* __restrict__ out, int N) {
    constexpr int TPN = D / 8;
    constexpr int NPB = 256 / TPN;
    const int tid = threadIdx.x;
    const int g = tid / TPN;
    const int lane = tid % TPN;
    const int node = blockIdx.x * NPB + g;
    if (node >= N) return;

    const int beg = row_ptr[node];
    const int end = row_ptr[node + 1];
    const float di = dinv[node];
    const half8 uself = *(const half8*)&H[(size_t)node * D + lane * 8];
    float b[8];
    *(float4*)&b[0] = *(const float4*)&bias[lane * 8];
    *(float4*)&b[4] = *(const float4*)&bias[lane * 8 + 4];

    float acc[8];
#pragma unroll
    for (int j = 0; j < 8; ++j) acc[j] = 0.0f;

    if (end > beg) {
        const int last = end - 1;
        int2 p0 = pairs[beg];
        int2 p1 = pairs[min(beg + 1, last)];
        int2 p2 = pairs[min(beg + 2, last)];
        int2 p3 = pairs[min(beg + 3, last)];
        int2 p4 = pairs[min(beg + 4, last)];
        half8 u0 = *(const half8*)&H[(size_t)p0.x * D + lane * 8];
        half8 u1 = *(const half8*)&H[(size_t)p1.x * D + lane * 8];
        half8 u2 = *(const half8*)&H[(size_t)p2.x * D + lane * 8];
        half8 u3 = *(const half8*)&H[(size_t)p3.x * D + lane * 8];
        for (int k = beg; k < end; ++k) {
            int2 p5 = pairs[min(k + 5, last)];
            half8 u4 = *(const half8*)&H[(size_t)p4.x * D + lane * 8];
            float w = __int_as_float(p0.y);
#pragma unroll
            for (int j = 0; j < 8; ++j) acc[j] = fmaf(w, (float)u0[j], acc[j]);
            p0 = p1; p1 = p2; p2 = p3; p3 = p4; p4 = p5;
            u0 = u1; u1 = u2; u2 = u3; u3 = u4;
        }
    }
    const float d2 = di * di;
#pragma unroll
    for (int j = 0; j < 8; ++j) acc[j] = fmaf(d2, (float)uself[j], acc[j]);
#pragma unroll
    for (int j = 0; j < 8; ++j) acc[j] = fmaxf(acc[j] + b[j], 0.f);

    if constexpr (sizeof(OUT) == 2) {
        half8 o;
#pragma unroll
        for (int j = 0; j < 8; ++j) o[j] = (_Float16)acc[j];
        *(half8*)&out[(size_t)node * D + lane * 8] = o;
    } else {
        float* dst = (float*)&out[(size_t)node * D + lane * 8];
        *(float4*)&dst[0] = make_float4(acc[0], acc[1], acc[2], acc[3]);
        *(float4*)&dst[4] = make_float4(acc[4], acc[5], acc[6], acc[7]);
    }
}

// ---------------------------------------------------------------- launch ----
extern "C" void kernel_launch(void* const* d_in, const int* in_sizes, int n_in,
                              void* d_out, int out_size, void* d_ws, size_t ws_size,
                              hipStream_t stream) {
    const float* x   = (const float*)d_in[0];
    const int* ei    = (const int*)d_in[1];
    const float* ew  = (const float*)d_in[2];
    const float* W1  = (const float*)d_in[3];
    const float* b1  = (const float*)d_in[4];
    const float* W2  = (const float*)d_in[5];
    const float* b2  = (const float*)d_in[6];
    const float* W3  = (const float*)d_in[7];
    const float* b3  = (const float*)d_in[8];
    float* out = (float*)d_out;

    const int N = in_sizes[0] / D0;   // 50000
    const int E = in_sizes[2];        // 800000
    (void)n_in; (void)out_size; (void)ws_size;

    // ---- workspace carving ----
    char* ws = (char*)d_ws;
    size_t off = 0;
    auto carve = [&](size_t bytes) -> void* {
        void* p = (void*)(ws + off);
        off += (bytes + 255) & ~(size_t)255;
        return p;
    };
    unsigned long long* pk = (unsigned long long*)carve((size_t)N * 8);
    float* dinv    = (float*)carve((size_t)N * 4);
    int*   cnt     = (int*)carve((size_t)N * 4);
    int*   row_ptr = (int*)carve((size_t)(N + 1) * 4);
    int*   rank    = (int*)carve((size_t)E * 4);
    int*   bsum    = (int*)carve(256 * 4);
    int2*  pairs   = (int2*)carve((size_t)E * 8);
    _Float16* bufH = (_Float16*)carve((size_t)N * D1 * 2);
    _Float16* bufO = (_Float16*)carve((size_t)N * D1 * 2);

    _Float16* h1 = bufH;              // N x 128 fp16 (gemm1 out)
    _Float16* h2 = bufO;              // N x 64  fp16 (agg1+gemm2 out)
    _Float16* h3 = bufH;              // N x 32  fp16 (agg2+gemm3 out; h1 dead)

    const int eb = (E + 255) / 256;       // 3125
    const int scanB = (N + 255) / 256;    // 196 (must be <= 256)
    const int gB = 768;                   // gemm1 blocks

    // ---- histogram (standalone: expose its true cost in counters) ----
    hipMemsetAsync(pk, 0, (size_t)N * 8, stream);
    hist_kernel<<<eb, 256, 0, stream>>>(ei, ew, pk, rank, E);

    // ---- CSR scan ----
    scan_reduce<<<scanB, 256, 0, stream>>>(pk, dinv, cnt, bsum, N);
    scan_apply<<<scanB, 256, 0, stream>>>(cnt, bsum, row_ptr, N, scanB);

    // ---- fused: gemm1 (LDS-staged A) + CSR fill (independent work) ----
    fillgemm_kernel<<<gB + eb, 256, 0, stream>>>(
        x, W1, h1, N, ei, ew, dinv, row_ptr, rank, pairs, E, gB);

    // ---- layer 1 aggregate (+ fused gemm2: 128 -> 64) ----
    agg_gemm_kernel<D1, D2><<<(N + 15) / 16, 256, 0, stream>>>(
        h1, row_ptr, pairs, dinv, b1, W2, h2, N);

    // ---- layer 2 aggregate (+ fused gemm3: 64 -> 32) ----
    agg_gemm_kernel<D2, D3><<<(N + 31) / 32, 256, 0, stream>>>(
        h2, row_ptr, pairs, dinv, b2, W3, h3, N);

    // ---- layer 3 aggregate + epilogue (fp32 out) ----
    agg_kernel<D3, float><<<(N + 63) / 64, 256, 0, stream>>>(
        h3, row_ptr, pairs, dinv, b3, out, N);
}